// Round 1
// baseline (498.949 us; speedup 1.0000x reference)
//
#include <hip/hip_runtime.h>

// Guided filter, B=4 H=1024 W=1024 C=4 f32 NHWC, r from d_in[2] (expected 40).
// Strategy: separable clamped box filters.
//   K1 kvert4 : vertical sliding sums of {I,p,Ip,II} -> ws f0..f3
//   K2 khorzAB: per-row prefix-scan horizontal box, compute A,b in-place -> f0,f1
//   K3 kvert2 : vertical sliding sums of {A,b} -> f2,f3
//   K4 khorzQ : horizontal box of {vA,vb} + q = meanA*I + meanb -> d_out
// N = box(ones) == cntH(h)*cntW(w), computed analytically.
// ws need: 4 * nb * 16 MiB; chunks over batches if ws_size is small.

#define HD 1024
#define WD 1024
#define CD 4
#define ROWF (WD * CD)              // floats per row = 4096
#define IMG ((size_t)HD * ROWF)     // floats per image
#define NPIX WD                     // float4 pixels per row
#define BH 128                      // vertical band height
#define NBANDS (HD / BH)
#define EPS 1e-8f

__device__ __forceinline__ float4 f4add(float4 a, float4 b) {
    return make_float4(a.x + b.x, a.y + b.y, a.z + b.z, a.w + b.w);
}
__device__ __forceinline__ float4 f4sub(float4 a, float4 b) {
    return make_float4(a.x - b.x, a.y - b.y, a.z - b.z, a.w - b.w);
}
__device__ __forceinline__ float4 f4s(float4 a, float s) {
    return make_float4(a.x * s, a.y * s, a.z * s, a.w * s);
}
__device__ __forceinline__ float4 shup4(float4 v, int d) {
    return make_float4(__shfl_up(v.x, d), __shfl_up(v.y, d), __shfl_up(v.z, d), __shfl_up(v.w, d));
}

// ---------------- K1: vertical sliding sums of I, p, I*p, I*I ----------------
__global__ __launch_bounds__(256) void kvert4(
    const float* __restrict__ I, const float* __restrict__ P,
    float* __restrict__ f0, float* __restrict__ f1,
    float* __restrict__ f2, float* __restrict__ f3,
    const int* __restrict__ rptr)
{
    const int r = *rptr;
    const int x = blockIdx.x * 256 + threadIdx.x;       // scalar column 0..4095
    const int h0 = blockIdx.y * BH, h1 = h0 + BH;
    const size_t base = (size_t)blockIdx.z * IMG + x;
    const float* Ib = I + base;
    const float* Pb = P + base;
    float* o0 = f0 + base; float* o1 = f1 + base;
    float* o2 = f2 + base; float* o3 = f3 + base;

    float sI = 0.f, sp = 0.f, sIp = 0.f, sII = 0.f;
    int lo = h0 - r; lo = lo < 0 ? 0 : lo;
    int hi = h0 + r; hi = hi > HD - 1 ? HD - 1 : hi;
    for (int j = lo; j <= hi; ++j) {
        float a = Ib[(size_t)j * ROWF], c = Pb[(size_t)j * ROWF];
        sI += a; sp += c; sIp += a * c; sII += a * a;
    }
    for (int h = h0;;) {
        size_t o = (size_t)h * ROWF;
        o0[o] = sI; o1[o] = sp; o2[o] = sIp; o3[o] = sII;
        if (++h >= h1) break;
        int ja = h + r;
        if (ja < HD) {
            float a = Ib[(size_t)ja * ROWF], c = Pb[(size_t)ja * ROWF];
            sI += a; sp += c; sIp += a * c; sII += a * a;
        }
        int js = h - r - 1;
        if (js >= 0) {
            float a = Ib[(size_t)js * ROWF], c = Pb[(size_t)js * ROWF];
            sI -= a; sp -= c; sIp -= a * c; sII -= a * a;
        }
    }
}

// ---------------- K3: vertical sliding sums of A, b ----------------
__global__ __launch_bounds__(256) void kvert2(
    const float* __restrict__ A, const float* __restrict__ Bf,
    float* __restrict__ f2, float* __restrict__ f3,
    const int* __restrict__ rptr)
{
    const int r = *rptr;
    const int x = blockIdx.x * 256 + threadIdx.x;
    const int h0 = blockIdx.y * BH, h1 = h0 + BH;
    const size_t base = (size_t)blockIdx.z * IMG + x;
    const float* Ab = A + base;
    const float* Bb = Bf + base;
    float* o2 = f2 + base; float* o3 = f3 + base;

    float sA = 0.f, sB = 0.f;
    int lo = h0 - r; lo = lo < 0 ? 0 : lo;
    int hi = h0 + r; hi = hi > HD - 1 ? HD - 1 : hi;
    for (int j = lo; j <= hi; ++j) {
        sA += Ab[(size_t)j * ROWF]; sB += Bb[(size_t)j * ROWF];
    }
    for (int h = h0;;) {
        size_t o = (size_t)h * ROWF;
        o2[o] = sA; o3[o] = sB;
        if (++h >= h1) break;
        int ja = h + r;
        if (ja < HD) { sA += Ab[(size_t)ja * ROWF]; sB += Bb[(size_t)ja * ROWF]; }
        int js = h - r - 1;
        if (js >= 0) { sA -= Ab[(size_t)js * ROWF]; sB -= Bb[(size_t)js * ROWF]; }
    }
}

// ---------------- K2: horizontal box of 4 fields + A,b (in-place rows) ----------------
__global__ __launch_bounds__(256) void khorzAB(
    float* __restrict__ f0, float* __restrict__ f1,
    const float* __restrict__ f2, const float* __restrict__ f3,
    const int* __restrict__ rptr)
{
    __shared__ float4 Pfx[NPIX + 1];
    __shared__ float4 wtot[4];
    const int r = *rptr;
    const int h = blockIdx.x;
    const int t = threadIdx.x;
    const int lane = t & 63, wv = t >> 6;
    const size_t rowb = ((size_t)blockIdx.y * HD + h) * NPIX;  // in float4 units

    int hl = h - r; hl = hl < 0 ? 0 : hl;
    int hh = h + r; hh = hh > HD - 1 ? HD - 1 : hh;
    const float cntH = (float)(hh - hl + 1);

    const float4* rows[4] = {
        (const float4*)f0 + rowb, (const float4*)f1 + rowb,
        (const float4*)f2 + rowb, (const float4*)f3 + rowb };

    float4 S[4][4];
    #pragma unroll
    for (int q = 0; q < 4; ++q) {
        float4 v0 = rows[q][4 * t + 0], v1 = rows[q][4 * t + 1];
        float4 v2 = rows[q][4 * t + 2], v3 = rows[q][4 * t + 3];
        float4 p0 = v0, p1 = f4add(p0, v1), p2 = f4add(p1, v2), p3 = f4add(p2, v3);
        float4 inc = p3;
        #pragma unroll
        for (int d = 1; d < 64; d <<= 1) {
            float4 tt = shup4(inc, d);
            if (lane >= d) inc = f4add(inc, tt);
        }
        float4 excl = shup4(inc, 1);
        if (lane == 0) excl = make_float4(0.f, 0.f, 0.f, 0.f);
        if (lane == 63) wtot[wv] = inc;
        __syncthreads();
        float4 base = excl;
        for (int wq = 0; wq < wv; ++wq) base = f4add(base, wtot[wq]);
        if (t == 0) Pfx[0] = make_float4(0.f, 0.f, 0.f, 0.f);
        Pfx[4 * t + 1] = f4add(base, p0);
        Pfx[4 * t + 2] = f4add(base, p1);
        Pfx[4 * t + 3] = f4add(base, p2);
        Pfx[4 * t + 4] = f4add(base, p3);
        __syncthreads();
        #pragma unroll
        for (int i = 0; i < 4; ++i) {
            int wp = 4 * t + i;
            int wl = wp - r; wl = wl < 0 ? 0 : wl;
            int wh = wp + r; wh = wh > NPIX - 1 ? NPIX - 1 : wh;
            S[q][i] = f4sub(Pfx[wh + 1], Pfx[wl]);
        }
        __syncthreads();
    }

    float4* oA = (float4*)f0 + rowb;
    float4* oB = (float4*)f1 + rowb;
    #pragma unroll
    for (int i = 0; i < 4; ++i) {
        int wp = 4 * t + i;
        int wl = wp - r; wl = wl < 0 ? 0 : wl;
        int wh = wp + r; wh = wh > NPIX - 1 ? NPIX - 1 : wh;
        float invN = 1.0f / ((float)(wh - wl + 1) * cntH);
        float4 mI = f4s(S[0][i], invN), mp = f4s(S[1][i], invN);
        float4 mIp = f4s(S[2][i], invN), mII = f4s(S[3][i], invN);
        float4 cov = make_float4(mIp.x - mI.x * mp.x, mIp.y - mI.y * mp.y,
                                 mIp.z - mI.z * mp.z, mIp.w - mI.w * mp.w);
        float4 var = make_float4(mII.x - mI.x * mI.x, mII.y - mI.y * mI.y,
                                 mII.z - mI.z * mI.z, mII.w - mI.w * mI.w);
        float4 Av = make_float4(cov.x / (var.x + EPS), cov.y / (var.y + EPS),
                                cov.z / (var.z + EPS), cov.w / (var.w + EPS));
        float4 Bv = make_float4(mp.x - Av.x * mI.x, mp.y - Av.y * mI.y,
                                mp.z - Av.z * mI.z, mp.w - Av.w * mI.w);
        oA[wp] = Av;
        oB[wp] = Bv;
    }
}

// ---------------- K4: horizontal box of vA,vb + q = meanA*I + meanb ----------------
__global__ __launch_bounds__(256) void khorzQ(
    const float* __restrict__ g0, const float* __restrict__ g1,
    const float* __restrict__ I, float* __restrict__ out,
    const int* __restrict__ rptr)
{
    __shared__ float4 Pfx[NPIX + 1];
    __shared__ float4 wtot[4];
    const int r = *rptr;
    const int h = blockIdx.x;
    const int t = threadIdx.x;
    const int lane = t & 63, wv = t >> 6;
    const size_t rowb = ((size_t)blockIdx.y * HD + h) * NPIX;

    int hl = h - r; hl = hl < 0 ? 0 : hl;
    int hh = h + r; hh = hh > HD - 1 ? HD - 1 : hh;
    const float cntH = (float)(hh - hl + 1);

    const float4* rows[2] = { (const float4*)g0 + rowb, (const float4*)g1 + rowb };

    float4 S[2][4];
    #pragma unroll
    for (int q = 0; q < 2; ++q) {
        float4 v0 = rows[q][4 * t + 0], v1 = rows[q][4 * t + 1];
        float4 v2 = rows[q][4 * t + 2], v3 = rows[q][4 * t + 3];
        float4 p0 = v0, p1 = f4add(p0, v1), p2 = f4add(p1, v2), p3 = f4add(p2, v3);
        float4 inc = p3;
        #pragma unroll
        for (int d = 1; d < 64; d <<= 1) {
            float4 tt = shup4(inc, d);
            if (lane >= d) inc = f4add(inc, tt);
        }
        float4 excl = shup4(inc, 1);
        if (lane == 0) excl = make_float4(0.f, 0.f, 0.f, 0.f);
        if (lane == 63) wtot[wv] = inc;
        __syncthreads();
        float4 base = excl;
        for (int wq = 0; wq < wv; ++wq) base = f4add(base, wtot[wq]);
        if (t == 0) Pfx[0] = make_float4(0.f, 0.f, 0.f, 0.f);
        Pfx[4 * t + 1] = f4add(base, p0);
        Pfx[4 * t + 2] = f4add(base, p1);
        Pfx[4 * t + 3] = f4add(base, p2);
        Pfx[4 * t + 4] = f4add(base, p3);
        __syncthreads();
        #pragma unroll
        for (int i = 0; i < 4; ++i) {
            int wp = 4 * t + i;
            int wl = wp - r; wl = wl < 0 ? 0 : wl;
            int wh = wp + r; wh = wh > NPIX - 1 ? NPIX - 1 : wh;
            S[q][i] = f4sub(Pfx[wh + 1], Pfx[wl]);
        }
        __syncthreads();
    }

    const float4* Irow = (const float4*)I + rowb;
    float4* orow = (float4*)out + rowb;
    #pragma unroll
    for (int i = 0; i < 4; ++i) {
        int wp = 4 * t + i;
        int wl = wp - r; wl = wl < 0 ? 0 : wl;
        int wh = wp + r; wh = wh > NPIX - 1 ? NPIX - 1 : wh;
        float invN = 1.0f / ((float)(wh - wl + 1) * cntH);
        float4 mA = f4s(S[0][i], invN);
        float4 mB = f4s(S[1][i], invN);
        float4 iv = Irow[wp];
        orow[wp] = make_float4(mA.x * iv.x + mB.x, mA.y * iv.y + mB.y,
                               mA.z * iv.z + mB.z, mA.w * iv.w + mB.w);
    }
}

extern "C" void kernel_launch(void* const* d_in, const int* in_sizes, int n_in,
                              void* d_out, int out_size, void* d_ws, size_t ws_size,
                              hipStream_t stream)
{
    const float* I = (const float*)d_in[0];
    const float* P = (const float*)d_in[1];
    const int* rptr = (const int*)d_in[2];
    float* out = (float*)d_out;

    const int B = (int)(in_sizes[0] / IMG);            // 4
    const size_t imgBytes = IMG * sizeof(float);       // 16 MiB
    const size_t perBatchWs = 4 * imgBytes;            // 64 MiB

    int nbChunk = (int)(ws_size / perBatchWs);
    if (nbChunk < 1) nbChunk = 1;
    if (nbChunk > B) nbChunk = B;

    for (int b0 = 0; b0 < B; b0 += nbChunk) {
        const int nb = (b0 + nbChunk <= B) ? nbChunk : (B - b0);
        float* f0 = (float*)d_ws;
        float* f1 = f0 + (size_t)nb * IMG;
        float* f2 = f1 + (size_t)nb * IMG;
        float* f3 = f2 + (size_t)nb * IMG;
        const float* Ib = I + (size_t)b0 * IMG;
        const float* Pb = P + (size_t)b0 * IMG;
        float* ob = out + (size_t)b0 * IMG;

        dim3 gv(ROWF / 256, NBANDS, nb);
        dim3 gh(HD, nb);
        kvert4<<<gv, 256, 0, stream>>>(Ib, Pb, f0, f1, f2, f3, rptr);
        khorzAB<<<gh, 256, 0, stream>>>(f0, f1, f2, f3, rptr);
        kvert2<<<gv, 256, 0, stream>>>(f0, f1, f2, f3, rptr);
        khorzQ<<<gh, 256, 0, stream>>>(f2, f3, Ib, ob, rptr);
    }
}

// Round 2
// 340.693 us; speedup vs baseline: 1.4645x; 1.4645x over previous
//
#include <hip/hip_runtime.h>

// Guided filter, B=4 H=1024 W=1024 C=4 f32 NHWC, r from d_in[2] (expected 40).
// Separable clamped box filters:
//   K1 kvert4 : vertical sliding sums of {I,p,Ip,II} -> ws f0..f3
//   K2 khorzAB: per-row prefix-scan horizontal box, compute A,b in-place -> f0,f1
//   K3 kvert2 : vertical sliding sums of {A,b} -> f2,f3
//   K4 khorzQ : horizontal box of {vA,vb} + q = meanA*I + meanb -> d_out
// N = box(ones) == cntH(h)*cntW(w), analytic.
// R1->R2: vertical kernels rewritten branchless + unrolled, BH 128->64
// (16 waves/CU) to break the latency-serialized sliding-window chain.

#define HD 1024
#define WD 1024
#define CD 4
#define ROWF (WD * CD)              // floats per row = 4096
#define IMG ((size_t)HD * ROWF)     // floats per image
#define NPIX WD                     // float4 pixels per row
#define BH 64                       // vertical band height
#define NBANDS (HD / BH)
#define EPS 1e-8f

__device__ __forceinline__ float4 f4add(float4 a, float4 b) {
    return make_float4(a.x + b.x, a.y + b.y, a.z + b.z, a.w + b.w);
}
__device__ __forceinline__ float4 f4sub(float4 a, float4 b) {
    return make_float4(a.x - b.x, a.y - b.y, a.z - b.z, a.w - b.w);
}
__device__ __forceinline__ float4 f4s(float4 a, float s) {
    return make_float4(a.x * s, a.y * s, a.z * s, a.w * s);
}
__device__ __forceinline__ float4 shup4(float4 v, int d) {
    return make_float4(__shfl_up(v.x, d), __shfl_up(v.y, d), __shfl_up(v.z, d), __shfl_up(v.w, d));
}

// ---------------- K1: vertical sliding sums of I, p, I*p, I*I ----------------
__global__ __launch_bounds__(256) void kvert4(
    const float* __restrict__ I, const float* __restrict__ P,
    float* __restrict__ f0, float* __restrict__ f1,
    float* __restrict__ f2, float* __restrict__ f3,
    const int* __restrict__ rptr)
{
    const int r = *rptr;
    const int x = blockIdx.x * 256 + threadIdx.x;       // scalar column 0..4095
    const int h0 = blockIdx.y * BH;
    const size_t base = (size_t)blockIdx.z * IMG + x;
    const float* Ib = I + base;
    const float* Pb = P + base;
    float* o0 = f0 + base; float* o1 = f1 + base;
    float* o2 = f2 + base; float* o3 = f3 + base;

    float sI = 0.f, sp = 0.f, sIp = 0.f, sII = 0.f;
    int lo = h0 - r; lo = lo < 0 ? 0 : lo;
    int hi = h0 + r; hi = hi > HD - 1 ? HD - 1 : hi;
    #pragma unroll 4
    for (int j = lo; j <= hi; ++j) {
        float a = Ib[(size_t)j * ROWF], c = Pb[(size_t)j * ROWF];
        sI += a; sp += c; sIp += a * c; sII += a * a;
    }
    #pragma unroll 8
    for (int h = h0; h < h0 + BH; ++h) {
        size_t o = (size_t)h * ROWF;
        o0[o] = sI; o1[o] = sp; o2[o] = sIp; o3[o] = sII;
        // prepare h+1 (branchless; last iteration's update is dead but harmless)
        int ja = h + 1 + r;
        int js = h - r;
        float wa = (ja <= HD - 1) ? 1.f : 0.f;
        float ws = (js >= 0) ? 1.f : 0.f;
        int jac = (ja <= HD - 1) ? ja : HD - 1;
        int jsc = (js >= 0) ? js : 0;
        float a1 = Ib[(size_t)jac * ROWF] * wa, c1 = Pb[(size_t)jac * ROWF] * wa;
        float a2 = Ib[(size_t)jsc * ROWF] * ws, c2 = Pb[(size_t)jsc * ROWF] * ws;
        sI  += a1 - a2;
        sp  += c1 - c2;
        sIp += a1 * c1 - a2 * c2;
        sII += a1 * a1 - a2 * a2;
    }
}

// ---------------- K3: vertical sliding sums of A, b ----------------
__global__ __launch_bounds__(256) void kvert2(
    const float* __restrict__ A, const float* __restrict__ Bf,
    float* __restrict__ f2, float* __restrict__ f3,
    const int* __restrict__ rptr)
{
    const int r = *rptr;
    const int x = blockIdx.x * 256 + threadIdx.x;
    const int h0 = blockIdx.y * BH;
    const size_t base = (size_t)blockIdx.z * IMG + x;
    const float* Ab = A + base;
    const float* Bb = Bf + base;
    float* o2 = f2 + base; float* o3 = f3 + base;

    float sA = 0.f, sB = 0.f;
    int lo = h0 - r; lo = lo < 0 ? 0 : lo;
    int hi = h0 + r; hi = hi > HD - 1 ? HD - 1 : hi;
    #pragma unroll 4
    for (int j = lo; j <= hi; ++j) {
        sA += Ab[(size_t)j * ROWF]; sB += Bb[(size_t)j * ROWF];
    }
    #pragma unroll 8
    for (int h = h0; h < h0 + BH; ++h) {
        size_t o = (size_t)h * ROWF;
        o2[o] = sA; o3[o] = sB;
        int ja = h + 1 + r;
        int js = h - r;
        float wa = (ja <= HD - 1) ? 1.f : 0.f;
        float ws = (js >= 0) ? 1.f : 0.f;
        int jac = (ja <= HD - 1) ? ja : HD - 1;
        int jsc = (js >= 0) ? js : 0;
        float a1 = Ab[(size_t)jac * ROWF] * wa, b1 = Bb[(size_t)jac * ROWF] * wa;
        float a2 = Ab[(size_t)jsc * ROWF] * ws, b2 = Bb[(size_t)jsc * ROWF] * ws;
        sA += a1 - a2;
        sB += b1 - b2;
    }
}

// ---------------- K2: horizontal box of 4 fields + A,b (in-place rows) ----------------
__global__ __launch_bounds__(256) void khorzAB(
    float* __restrict__ f0, float* __restrict__ f1,
    const float* __restrict__ f2, const float* __restrict__ f3,
    const int* __restrict__ rptr)
{
    __shared__ float4 Pfx[NPIX + 1];
    __shared__ float4 wtot[4];
    const int r = *rptr;
    const int h = blockIdx.x;
    const int t = threadIdx.x;
    const int lane = t & 63, wv = t >> 6;
    const size_t rowb = ((size_t)blockIdx.y * HD + h) * NPIX;  // in float4 units

    int hl = h - r; hl = hl < 0 ? 0 : hl;
    int hh = h + r; hh = hh > HD - 1 ? HD - 1 : hh;
    const float cntH = (float)(hh - hl + 1);

    const float4* rows[4] = {
        (const float4*)f0 + rowb, (const float4*)f1 + rowb,
        (const float4*)f2 + rowb, (const float4*)f3 + rowb };

    float4 S[4][4];
    #pragma unroll
    for (int q = 0; q < 4; ++q) {
        float4 v0 = rows[q][4 * t + 0], v1 = rows[q][4 * t + 1];
        float4 v2 = rows[q][4 * t + 2], v3 = rows[q][4 * t + 3];
        float4 p0 = v0, p1 = f4add(p0, v1), p2 = f4add(p1, v2), p3 = f4add(p2, v3);
        float4 inc = p3;
        #pragma unroll
        for (int d = 1; d < 64; d <<= 1) {
            float4 tt = shup4(inc, d);
            if (lane >= d) inc = f4add(inc, tt);
        }
        float4 excl = shup4(inc, 1);
        if (lane == 0) excl = make_float4(0.f, 0.f, 0.f, 0.f);
        if (lane == 63) wtot[wv] = inc;
        __syncthreads();
        float4 base = excl;
        for (int wq = 0; wq < wv; ++wq) base = f4add(base, wtot[wq]);
        if (t == 0) Pfx[0] = make_float4(0.f, 0.f, 0.f, 0.f);
        Pfx[4 * t + 1] = f4add(base, p0);
        Pfx[4 * t + 2] = f4add(base, p1);
        Pfx[4 * t + 3] = f4add(base, p2);
        Pfx[4 * t + 4] = f4add(base, p3);
        __syncthreads();
        #pragma unroll
        for (int i = 0; i < 4; ++i) {
            int wp = 4 * t + i;
            int wl = wp - r; wl = wl < 0 ? 0 : wl;
            int wh = wp + r; wh = wh > NPIX - 1 ? NPIX - 1 : wh;
            S[q][i] = f4sub(Pfx[wh + 1], Pfx[wl]);
        }
        __syncthreads();
    }

    float4* oA = (float4*)f0 + rowb;
    float4* oB = (float4*)f1 + rowb;
    #pragma unroll
    for (int i = 0; i < 4; ++i) {
        int wp = 4 * t + i;
        int wl = wp - r; wl = wl < 0 ? 0 : wl;
        int wh = wp + r; wh = wh > NPIX - 1 ? NPIX - 1 : wh;
        float invN = 1.0f / ((float)(wh - wl + 1) * cntH);
        float4 mI = f4s(S[0][i], invN), mp = f4s(S[1][i], invN);
        float4 mIp = f4s(S[2][i], invN), mII = f4s(S[3][i], invN);
        float4 cov = make_float4(mIp.x - mI.x * mp.x, mIp.y - mI.y * mp.y,
                                 mIp.z - mI.z * mp.z, mIp.w - mI.w * mp.w);
        float4 var = make_float4(mII.x - mI.x * mI.x, mII.y - mI.y * mI.y,
                                 mII.z - mI.z * mI.z, mII.w - mI.w * mI.w);
        float4 Av = make_float4(cov.x / (var.x + EPS), cov.y / (var.y + EPS),
                                cov.z / (var.z + EPS), cov.w / (var.w + EPS));
        float4 Bv = make_float4(mp.x - Av.x * mI.x, mp.y - Av.y * mI.y,
                                mp.z - Av.z * mI.z, mp.w - Av.w * mI.w);
        oA[wp] = Av;
        oB[wp] = Bv;
    }
}

// ---------------- K4: horizontal box of vA,vb + q = meanA*I + meanb ----------------
__global__ __launch_bounds__(256) void khorzQ(
    const float* __restrict__ g0, const float* __restrict__ g1,
    const float* __restrict__ I, float* __restrict__ out,
    const int* __restrict__ rptr)
{
    __shared__ float4 Pfx[NPIX + 1];
    __shared__ float4 wtot[4];
    const int r = *rptr;
    const int h = blockIdx.x;
    const int t = threadIdx.x;
    const int lane = t & 63, wv = t >> 6;
    const size_t rowb = ((size_t)blockIdx.y * HD + h) * NPIX;

    int hl = h - r; hl = hl < 0 ? 0 : hl;
    int hh = h + r; hh = hh > HD - 1 ? HD - 1 : hh;
    const float cntH = (float)(hh - hl + 1);

    const float4* rows[2] = { (const float4*)g0 + rowb, (const float4*)g1 + rowb };

    float4 S[2][4];
    #pragma unroll
    for (int q = 0; q < 2; ++q) {
        float4 v0 = rows[q][4 * t + 0], v1 = rows[q][4 * t + 1];
        float4 v2 = rows[q][4 * t + 2], v3 = rows[q][4 * t + 3];
        float4 p0 = v0, p1 = f4add(p0, v1), p2 = f4add(p1, v2), p3 = f4add(p2, v3);
        float4 inc = p3;
        #pragma unroll
        for (int d = 1; d < 64; d <<= 1) {
            float4 tt = shup4(inc, d);
            if (lane >= d) inc = f4add(inc, tt);
        }
        float4 excl = shup4(inc, 1);
        if (lane == 0) excl = make_float4(0.f, 0.f, 0.f, 0.f);
        if (lane == 63) wtot[wv] = inc;
        __syncthreads();
        float4 base = excl;
        for (int wq = 0; wq < wv; ++wq) base = f4add(base, wtot[wq]);
        if (t == 0) Pfx[0] = make_float4(0.f, 0.f, 0.f, 0.f);
        Pfx[4 * t + 1] = f4add(base, p0);
        Pfx[4 * t + 2] = f4add(base, p1);
        Pfx[4 * t + 3] = f4add(base, p2);
        Pfx[4 * t + 4] = f4add(base, p3);
        __syncthreads();
        #pragma unroll
        for (int i = 0; i < 4; ++i) {
            int wp = 4 * t + i;
            int wl = wp - r; wl = wl < 0 ? 0 : wl;
            int wh = wp + r; wh = wh > NPIX - 1 ? NPIX - 1 : wh;
            S[q][i] = f4sub(Pfx[wh + 1], Pfx[wl]);
        }
        __syncthreads();
    }

    const float4* Irow = (const float4*)I + rowb;
    float4* orow = (float4*)out + rowb;
    #pragma unroll
    for (int i = 0; i < 4; ++i) {
        int wp = 4 * t + i;
        int wl = wp - r; wl = wl < 0 ? 0 : wl;
        int wh = wp + r; wh = wh > NPIX - 1 ? NPIX - 1 : wh;
        float invN = 1.0f / ((float)(wh - wl + 1) * cntH);
        float4 mA = f4s(S[0][i], invN);
        float4 mB = f4s(S[1][i], invN);
        float4 iv = Irow[wp];
        orow[wp] = make_float4(mA.x * iv.x + mB.x, mA.y * iv.y + mB.y,
                               mA.z * iv.z + mB.z, mA.w * iv.w + mB.w);
    }
}

extern "C" void kernel_launch(void* const* d_in, const int* in_sizes, int n_in,
                              void* d_out, int out_size, void* d_ws, size_t ws_size,
                              hipStream_t stream)
{
    const float* I = (const float*)d_in[0];
    const float* P = (const float*)d_in[1];
    const int* rptr = (const int*)d_in[2];
    float* out = (float*)d_out;

    const int B = (int)(in_sizes[0] / IMG);            // 4
    const size_t imgBytes = IMG * sizeof(float);       // 16 MiB
    const size_t perBatchWs = 4 * imgBytes;            // 64 MiB

    int nbChunk = (int)(ws_size / perBatchWs);
    if (nbChunk < 1) nbChunk = 1;
    if (nbChunk > B) nbChunk = B;

    for (int b0 = 0; b0 < B; b0 += nbChunk) {
        const int nb = (b0 + nbChunk <= B) ? nbChunk : (B - b0);
        float* f0 = (float*)d_ws;
        float* f1 = f0 + (size_t)nb * IMG;
        float* f2 = f1 + (size_t)nb * IMG;
        float* f3 = f2 + (size_t)nb * IMG;
        const float* Ib = I + (size_t)b0 * IMG;
        const float* Pb = P + (size_t)b0 * IMG;
        float* ob = out + (size_t)b0 * IMG;

        dim3 gv(ROWF / 256, NBANDS, nb);
        dim3 gh(HD, nb);
        kvert4<<<gv, 256, 0, stream>>>(Ib, Pb, f0, f1, f2, f3, rptr);
        khorzAB<<<gh, 256, 0, stream>>>(f0, f1, f2, f3, rptr);
        kvert2<<<gv, 256, 0, stream>>>(f0, f1, f2, f3, rptr);
        khorzQ<<<gh, 256, 0, stream>>>(f2, f3, Ib, ob, rptr);
    }
}

// Round 3
// 330.838 us; speedup vs baseline: 1.5081x; 1.0298x over previous
//
#include <hip/hip_runtime.h>
#include <hip/hip_fp16.h>

// Guided filter, B=4 H=1024 W=1024 C=4 f32 NHWC, r from d_in[2] (expected 40).
// Separable clamped box filters:
//   K1 kvert4 : vertical sliding sums of {I,p,Ip,II} -> fp16 fields hf0..hf3
//   K2 khorzAB: per-row prefix-scan horizontal box of hf*, compute A,b (f32)
//   K3 kvert2 : vertical sliding sums of {A,b} -> vA,vb (f32, overwrite hf region)
//   K4 khorzQ : horizontal box of {vA,vb} + q = meanA*I + meanb -> d_out
// N = box(ones) == cntH(h)*cntW(w), analytic.
// R2->R3: verticals vectorized to float4/lane + BH=32 (2048 blocks, full
// occupancy); intermediate vertical-sum fields stored fp16 (halves traffic).

#define HD 1024
#define WD 1024
#define CD 4
#define ROWF (WD * CD)              // floats per row = 4096
#define ROW4 (WD)                   // float4 pixels per row = 1024
#define IMG ((size_t)HD * ROWF)     // floats per image
#define IMG4 ((size_t)HD * ROW4)    // float4 pixels per image
#define NPIX WD
#define BH 32                       // vertical band height
#define NBANDS (HD / BH)
#define EPS 1e-8f

struct H4 { __half2 lo, hi; };      // 8 bytes: one fp16 pixel (4 channels)

__device__ __forceinline__ H4 pack4(float4 v) {
    H4 h; h.lo = __floats2half2_rn(v.x, v.y); h.hi = __floats2half2_rn(v.z, v.w);
    return h;
}
__device__ __forceinline__ float4 unpack4(H4 h) {
    float2 l = __half22float2(h.lo), u = __half22float2(h.hi);
    return make_float4(l.x, l.y, u.x, u.y);
}
__device__ __forceinline__ float4 f4add(float4 a, float4 b) {
    return make_float4(a.x + b.x, a.y + b.y, a.z + b.z, a.w + b.w);
}
__device__ __forceinline__ float4 f4sub(float4 a, float4 b) {
    return make_float4(a.x - b.x, a.y - b.y, a.z - b.z, a.w - b.w);
}
__device__ __forceinline__ float4 f4s(float4 a, float s) {
    return make_float4(a.x * s, a.y * s, a.z * s, a.w * s);
}
__device__ __forceinline__ float4 shup4(float4 v, int d) {
    return make_float4(__shfl_up(v.x, d), __shfl_up(v.y, d), __shfl_up(v.z, d), __shfl_up(v.w, d));
}

// ---------------- K1: vertical sliding sums of I, p, I*p, I*I (fp16 out) ----------------
__global__ __launch_bounds__(256) void kvert4(
    const float4* __restrict__ I4, const float4* __restrict__ P4,
    H4* __restrict__ o0, H4* __restrict__ o1,
    H4* __restrict__ o2, H4* __restrict__ o3,
    const int* __restrict__ rptr)
{
    const int r = *rptr;
    const int px = blockIdx.x * 256 + threadIdx.x;      // float4 pixel col 0..1023
    const int h0 = blockIdx.y * BH;
    const size_t ibase = (size_t)blockIdx.z * IMG4 + px;
    const float4* Ib = I4 + ibase;
    const float4* Pb = P4 + ibase;
    H4* p0 = o0 + ibase; H4* p1 = o1 + ibase;
    H4* p2 = o2 + ibase; H4* p3 = o3 + ibase;

    float4 sI = make_float4(0,0,0,0), sp = sI, sIp = sI, sII = sI;
    int lo = h0 - r; lo = lo < 0 ? 0 : lo;
    int hi = h0 + r; hi = hi > HD - 1 ? HD - 1 : hi;
    #pragma unroll 4
    for (int j = lo; j <= hi; ++j) {
        float4 a = Ib[(size_t)j * ROW4], c = Pb[(size_t)j * ROW4];
        sI = f4add(sI, a); sp = f4add(sp, c);
        sIp.x += a.x*c.x; sIp.y += a.y*c.y; sIp.z += a.z*c.z; sIp.w += a.w*c.w;
        sII.x += a.x*a.x; sII.y += a.y*a.y; sII.z += a.z*a.z; sII.w += a.w*a.w;
    }
    #pragma unroll 4
    for (int h = h0; h < h0 + BH; ++h) {
        size_t o = (size_t)h * ROW4;
        p0[o] = pack4(sI); p1[o] = pack4(sp);
        p2[o] = pack4(sIp); p3[o] = pack4(sII);
        int ja = h + 1 + r;
        int js = h - r;
        float wa = (ja <= HD - 1) ? 1.f : 0.f;
        float ws = (js >= 0) ? 1.f : 0.f;
        int jac = (ja <= HD - 1) ? ja : HD - 1;
        int jsc = (js >= 0) ? js : 0;
        float4 a1 = Ib[(size_t)jac * ROW4], c1 = Pb[(size_t)jac * ROW4];
        float4 a2 = Ib[(size_t)jsc * ROW4], c2 = Pb[(size_t)jsc * ROW4];
        a1 = f4s(a1, wa); c1 = f4s(c1, wa);
        a2 = f4s(a2, ws); c2 = f4s(c2, ws);
        sI = f4add(f4sub(sI, a2), a1);
        sp = f4add(f4sub(sp, c2), c1);
        sIp.x += a1.x*c1.x - a2.x*c2.x; sIp.y += a1.y*c1.y - a2.y*c2.y;
        sIp.z += a1.z*c1.z - a2.z*c2.z; sIp.w += a1.w*c1.w - a2.w*c2.w;
        sII.x += a1.x*a1.x - a2.x*a2.x; sII.y += a1.y*a1.y - a2.y*a2.y;
        sII.z += a1.z*a1.z - a2.z*a2.z; sII.w += a1.w*a1.w - a2.w*a2.w;
    }
}

// ---------------- K3: vertical sliding sums of A, b (f32) ----------------
__global__ __launch_bounds__(256) void kvert2(
    const float4* __restrict__ A4, const float4* __restrict__ B4,
    float4* __restrict__ oA, float4* __restrict__ oB,
    const int* __restrict__ rptr)
{
    const int r = *rptr;
    const int px = blockIdx.x * 256 + threadIdx.x;
    const int h0 = blockIdx.y * BH;
    const size_t ibase = (size_t)blockIdx.z * IMG4 + px;
    const float4* Ab = A4 + ibase;
    const float4* Bb = B4 + ibase;
    float4* pA = oA + ibase;
    float4* pB = oB + ibase;

    float4 sA = make_float4(0,0,0,0), sB = sA;
    int lo = h0 - r; lo = lo < 0 ? 0 : lo;
    int hi = h0 + r; hi = hi > HD - 1 ? HD - 1 : hi;
    #pragma unroll 4
    for (int j = lo; j <= hi; ++j) {
        sA = f4add(sA, Ab[(size_t)j * ROW4]);
        sB = f4add(sB, Bb[(size_t)j * ROW4]);
    }
    #pragma unroll 4
    for (int h = h0; h < h0 + BH; ++h) {
        size_t o = (size_t)h * ROW4;
        pA[o] = sA; pB[o] = sB;
        int ja = h + 1 + r;
        int js = h - r;
        float wa = (ja <= HD - 1) ? 1.f : 0.f;
        float ws = (js >= 0) ? 1.f : 0.f;
        int jac = (ja <= HD - 1) ? ja : HD - 1;
        int jsc = (js >= 0) ? js : 0;
        float4 a1 = f4s(Ab[(size_t)jac * ROW4], wa), b1 = f4s(Bb[(size_t)jac * ROW4], wa);
        float4 a2 = f4s(Ab[(size_t)jsc * ROW4], ws), b2 = f4s(Bb[(size_t)jsc * ROW4], ws);
        sA = f4add(f4sub(sA, a2), a1);
        sB = f4add(f4sub(sB, b2), b1);
    }
}

// ---------------- K2: horizontal box of 4 fp16 fields -> A,b (f32) ----------------
__global__ __launch_bounds__(256) void khorzAB(
    const H4* __restrict__ hf0, const H4* __restrict__ hf1,
    const H4* __restrict__ hf2, const H4* __restrict__ hf3,
    float* __restrict__ Aout, float* __restrict__ Bout,
    const int* __restrict__ rptr)
{
    __shared__ float4 Pfx[NPIX + 1];
    __shared__ float4 wtot[4];
    const int r = *rptr;
    const int h = blockIdx.x;
    const int t = threadIdx.x;
    const int lane = t & 63, wv = t >> 6;
    const size_t rowb = ((size_t)blockIdx.y * HD + h) * NPIX;  // in pixels

    int hl = h - r; hl = hl < 0 ? 0 : hl;
    int hh = h + r; hh = hh > HD - 1 ? HD - 1 : hh;
    const float cntH = (float)(hh - hl + 1);

    const H4* rows[4] = { hf0 + rowb, hf1 + rowb, hf2 + rowb, hf3 + rowb };

    float4 S[4][4];
    #pragma unroll
    for (int q = 0; q < 4; ++q) {
        float4 v0 = unpack4(rows[q][4 * t + 0]), v1 = unpack4(rows[q][4 * t + 1]);
        float4 v2 = unpack4(rows[q][4 * t + 2]), v3 = unpack4(rows[q][4 * t + 3]);
        float4 p0 = v0, p1 = f4add(p0, v1), p2 = f4add(p1, v2), p3 = f4add(p2, v3);
        float4 inc = p3;
        #pragma unroll
        for (int d = 1; d < 64; d <<= 1) {
            float4 tt = shup4(inc, d);
            if (lane >= d) inc = f4add(inc, tt);
        }
        float4 excl = shup4(inc, 1);
        if (lane == 0) excl = make_float4(0.f, 0.f, 0.f, 0.f);
        if (lane == 63) wtot[wv] = inc;
        __syncthreads();
        float4 base = excl;
        for (int wq = 0; wq < wv; ++wq) base = f4add(base, wtot[wq]);
        if (t == 0) Pfx[0] = make_float4(0.f, 0.f, 0.f, 0.f);
        Pfx[4 * t + 1] = f4add(base, p0);
        Pfx[4 * t + 2] = f4add(base, p1);
        Pfx[4 * t + 3] = f4add(base, p2);
        Pfx[4 * t + 4] = f4add(base, p3);
        __syncthreads();
        #pragma unroll
        for (int i = 0; i < 4; ++i) {
            int wp = 4 * t + i;
            int wl = wp - r; wl = wl < 0 ? 0 : wl;
            int wh = wp + r; wh = wh > NPIX - 1 ? NPIX - 1 : wh;
            S[q][i] = f4sub(Pfx[wh + 1], Pfx[wl]);
        }
        __syncthreads();
    }

    float4* oA = (float4*)Aout + rowb;
    float4* oB = (float4*)Bout + rowb;
    #pragma unroll
    for (int i = 0; i < 4; ++i) {
        int wp = 4 * t + i;
        int wl = wp - r; wl = wl < 0 ? 0 : wl;
        int wh = wp + r; wh = wh > NPIX - 1 ? NPIX - 1 : wh;
        float invN = 1.0f / ((float)(wh - wl + 1) * cntH);
        float4 mI = f4s(S[0][i], invN), mp = f4s(S[1][i], invN);
        float4 mIp = f4s(S[2][i], invN), mII = f4s(S[3][i], invN);
        float4 cov = make_float4(mIp.x - mI.x * mp.x, mIp.y - mI.y * mp.y,
                                 mIp.z - mI.z * mp.z, mIp.w - mI.w * mp.w);
        float4 var = make_float4(mII.x - mI.x * mI.x, mII.y - mI.y * mI.y,
                                 mII.z - mI.z * mI.z, mII.w - mI.w * mI.w);
        float4 Av = make_float4(cov.x / (var.x + EPS), cov.y / (var.y + EPS),
                                cov.z / (var.z + EPS), cov.w / (var.w + EPS));
        float4 Bv = make_float4(mp.x - Av.x * mI.x, mp.y - Av.y * mI.y,
                                mp.z - Av.z * mI.z, mp.w - Av.w * mI.w);
        oA[wp] = Av;
        oB[wp] = Bv;
    }
}

// ---------------- K4: horizontal box of vA,vb + q = meanA*I + meanb ----------------
__global__ __launch_bounds__(256) void khorzQ(
    const float* __restrict__ g0, const float* __restrict__ g1,
    const float* __restrict__ I, float* __restrict__ out,
    const int* __restrict__ rptr)
{
    __shared__ float4 Pfx[NPIX + 1];
    __shared__ float4 wtot[4];
    const int r = *rptr;
    const int h = blockIdx.x;
    const int t = threadIdx.x;
    const int lane = t & 63, wv = t >> 6;
    const size_t rowb = ((size_t)blockIdx.y * HD + h) * NPIX;

    int hl = h - r; hl = hl < 0 ? 0 : hl;
    int hh = h + r; hh = hh > HD - 1 ? HD - 1 : hh;
    const float cntH = (float)(hh - hl + 1);

    const float4* rows[2] = { (const float4*)g0 + rowb, (const float4*)g1 + rowb };

    float4 S[2][4];
    #pragma unroll
    for (int q = 0; q < 2; ++q) {
        float4 v0 = rows[q][4 * t + 0], v1 = rows[q][4 * t + 1];
        float4 v2 = rows[q][4 * t + 2], v3 = rows[q][4 * t + 3];
        float4 p0 = v0, p1 = f4add(p0, v1), p2 = f4add(p1, v2), p3 = f4add(p2, v3);
        float4 inc = p3;
        #pragma unroll
        for (int d = 1; d < 64; d <<= 1) {
            float4 tt = shup4(inc, d);
            if (lane >= d) inc = f4add(inc, tt);
        }
        float4 excl = shup4(inc, 1);
        if (lane == 0) excl = make_float4(0.f, 0.f, 0.f, 0.f);
        if (lane == 63) wtot[wv] = inc;
        __syncthreads();
        float4 base = excl;
        for (int wq = 0; wq < wv; ++wq) base = f4add(base, wtot[wq]);
        if (t == 0) Pfx[0] = make_float4(0.f, 0.f, 0.f, 0.f);
        Pfx[4 * t + 1] = f4add(base, p0);
        Pfx[4 * t + 2] = f4add(base, p1);
        Pfx[4 * t + 3] = f4add(base, p2);
        Pfx[4 * t + 4] = f4add(base, p3);
        __syncthreads();
        #pragma unroll
        for (int i = 0; i < 4; ++i) {
            int wp = 4 * t + i;
            int wl = wp - r; wl = wl < 0 ? 0 : wl;
            int wh = wp + r; wh = wh > NPIX - 1 ? NPIX - 1 : wh;
            S[q][i] = f4sub(Pfx[wh + 1], Pfx[wl]);
        }
        __syncthreads();
    }

    const float4* Irow = (const float4*)I + rowb;
    float4* orow = (float4*)out + rowb;
    #pragma unroll
    for (int i = 0; i < 4; ++i) {
        int wp = 4 * t + i;
        int wl = wp - r; wl = wl < 0 ? 0 : wl;
        int wh = wp + r; wh = wh > NPIX - 1 ? NPIX - 1 : wh;
        float invN = 1.0f / ((float)(wh - wl + 1) * cntH);
        float4 mA = f4s(S[0][i], invN);
        float4 mB = f4s(S[1][i], invN);
        float4 iv = Irow[wp];
        orow[wp] = make_float4(mA.x * iv.x + mB.x, mA.y * iv.y + mB.y,
                               mA.z * iv.z + mB.z, mA.w * iv.w + mB.w);
    }
}

extern "C" void kernel_launch(void* const* d_in, const int* in_sizes, int n_in,
                              void* d_out, int out_size, void* d_ws, size_t ws_size,
                              hipStream_t stream)
{
    const float* I = (const float*)d_in[0];
    const float* P = (const float*)d_in[1];
    const int* rptr = (const int*)d_in[2];
    float* out = (float*)d_out;

    const int B = (int)(in_sizes[0] / IMG);            // 4
    // ws per image: 4 half fields (32 MiB) + A,B f32 (32 MiB) = 64 MiB.
    // vA,vb (32 MiB f32) reuse the half-field region after K2 consumes it.
    const size_t perBatchWs = 4 * IMG * sizeof(float); // 64 MiB

    int nbChunk = (int)(ws_size / perBatchWs);
    if (nbChunk < 1) nbChunk = 1;
    if (nbChunk > B) nbChunk = B;

    for (int b0 = 0; b0 < B; b0 += nbChunk) {
        const int nb = (b0 + nbChunk <= B) ? nbChunk : (B - b0);
        H4* hf0 = (H4*)d_ws;                       // nb*IMG4 H4 each
        H4* hf1 = hf0 + (size_t)nb * IMG4;
        H4* hf2 = hf1 + (size_t)nb * IMG4;
        H4* hf3 = hf2 + (size_t)nb * IMG4;
        float* A  = (float*)(hf3 + (size_t)nb * IMG4);
        float* Bf = A + (size_t)nb * IMG;
        float* vA = (float*)d_ws;                  // overwrites hf region (after K2)
        float* vB = vA + (size_t)nb * IMG;

        const float* Ib = I + (size_t)b0 * IMG;
        const float* Pb = P + (size_t)b0 * IMG;
        float* ob = out + (size_t)b0 * IMG;

        dim3 gv(ROW4 / 256, NBANDS, nb);           // (4, 32, nb)
        dim3 gh(HD, nb);
        kvert4<<<gv, 256, 0, stream>>>((const float4*)Ib, (const float4*)Pb,
                                       hf0, hf1, hf2, hf3, rptr);
        khorzAB<<<gh, 256, 0, stream>>>(hf0, hf1, hf2, hf3, A, Bf, rptr);
        kvert2<<<gv, 256, 0, stream>>>((const float4*)A, (const float4*)Bf,
                                       (float4*)vA, (float4*)vB, rptr);
        khorzQ<<<gh, 256, 0, stream>>>(vA, vB, Ib, ob, rptr);
    }
}

// Round 4
// 266.386 us; speedup vs baseline: 1.8730x; 1.2419x over previous
//
#include <hip/hip_runtime.h>
#include <hip/hip_fp16.h>

// Guided filter, B=4 H=1024 W=1024 C=4 f32 NHWC, r from d_in[2] (expected 40).
// R3->R4: fully fused per box-pass. Two kernels:
//   kfusedAB: block spans full row width; vertical sliding sums of
//             {I,p,Ip,II} kept in registers; per output row a block-wide
//             prefix scan gives the horizontal box; emits A,b (fp16).
//   kfusedQ : same structure over {A,b}; q = meanA*I + meanb -> d_out (f32).
// N = cntH(h)*cntW(w) analytic. Grid = 64 bands x batches = 256 blocks
// (1 block/CU, 4 waves, max VGPRs). Warm-up re-reads are L3-served
// (I,p = 128 MB and A,b = 64 MB both fit in 256 MB Infinity Cache).

#define HD 1024
#define WD 1024
#define ROW4 WD                      // float4 pixels per row
#define IMG4 ((size_t)HD * ROW4)     // pixels per image
#define IMGF (IMG4 * 4)              // floats per image
#define BH 16                        // output rows per block
#define NB (HD / BH)                 // 64 bands
#define EPS 1e-8f

struct H4 { __half2 lo, hi; };       // one fp16 pixel (4 channels)

__device__ __forceinline__ H4 pack4(float4 v) {
    H4 h; h.lo = __floats2half2_rn(v.x, v.y); h.hi = __floats2half2_rn(v.z, v.w);
    return h;
}
__device__ __forceinline__ float4 unpack4(H4 h) {
    float2 l = __half22float2(h.lo), u = __half22float2(h.hi);
    return make_float4(l.x, l.y, u.x, u.y);
}
__device__ __forceinline__ float4 f4add(float4 a, float4 b) {
    return make_float4(a.x + b.x, a.y + b.y, a.z + b.z, a.w + b.w);
}
__device__ __forceinline__ float4 f4sub(float4 a, float4 b) {
    return make_float4(a.x - b.x, a.y - b.y, a.z - b.z, a.w - b.w);
}
__device__ __forceinline__ float4 f4s(float4 a, float s) {
    return make_float4(a.x * s, a.y * s, a.z * s, a.w * s);
}
__device__ __forceinline__ float4 f4mul(float4 a, float4 b) {
    return make_float4(a.x * b.x, a.y * b.y, a.z * b.z, a.w * b.w);
}
__device__ __forceinline__ float4 shup4(float4 v, int d) {
    return make_float4(__shfl_up(v.x, d), __shfl_up(v.y, d), __shfl_up(v.z, d), __shfl_up(v.w, d));
}

// Block-wide inclusive prefix of two fields (4 float4/thread each) into
// Pfx[f][0..ROW4], Pfx[f][0] = 0. Two internal __syncthreads; Pfx valid on
// return. Caller must __syncthreads() after consuming Pfx before next call.
__device__ __forceinline__ void scan2(
    float4 (*Pfx)[ROW4 + 1], float4* wtot,    // wtot[wave*2 + field], 8 slots
    const float4* s0, const float4* s1, int t, int lane, int wv)
{
    const float4 z4 = make_float4(0.f, 0.f, 0.f, 0.f);
    float4 p0[4], p1[4];
    p0[0] = s0[0]; p1[0] = s1[0];
    #pragma unroll
    for (int i = 1; i < 4; ++i) {
        p0[i] = f4add(p0[i - 1], s0[i]);
        p1[i] = f4add(p1[i - 1], s1[i]);
    }
    float4 i0 = p0[3], i1 = p1[3];
    #pragma unroll
    for (int d = 1; d < 64; d <<= 1) {
        float4 t0 = shup4(i0, d), t1 = shup4(i1, d);
        if (lane >= d) { i0 = f4add(i0, t0); i1 = f4add(i1, t1); }
    }
    float4 e0 = shup4(i0, 1), e1 = shup4(i1, 1);
    if (lane == 0) { e0 = z4; e1 = z4; }
    if (lane == 63) { wtot[wv * 2 + 0] = i0; wtot[wv * 2 + 1] = i1; }
    __syncthreads();
    for (int wq = 0; wq < wv; ++wq) {
        e0 = f4add(e0, wtot[wq * 2 + 0]);
        e1 = f4add(e1, wtot[wq * 2 + 1]);
    }
    if (t == 0) { Pfx[0][0] = z4; Pfx[1][0] = z4; }
    #pragma unroll
    for (int i = 0; i < 4; ++i) {
        Pfx[0][4 * t + 1 + i] = f4add(e0, p0[i]);
        Pfx[1][4 * t + 1 + i] = f4add(e1, p1[i]);
    }
    __syncthreads();
}

// ---------------- KA: I,p -> A,b (fp16) ----------------
__global__ __launch_bounds__(256, 1) void kfusedAB(
    const float4* __restrict__ I4, const float4* __restrict__ P4,
    H4* __restrict__ Aout, H4* __restrict__ Bout,
    const int* __restrict__ rptr)
{
    __shared__ float4 Pfx[2][ROW4 + 1];
    __shared__ float4 wtot[8];
    const int r = *rptr;
    const int t = threadIdx.x, lane = t & 63, wv = t >> 6;
    const int h0 = blockIdx.x * BH;
    const size_t imgb = (size_t)blockIdx.y * IMG4;
    const float4* Ib = I4 + imgb + 4 * t;   // thread's 4 pixels folded in
    const float4* Pb = P4 + imgb + 4 * t;
    H4* Ao = Aout + imgb;
    H4* Bo = Bout + imgb;
    const float4 z4 = make_float4(0.f, 0.f, 0.f, 0.f);

    float4 sI[4], sp[4], sIp[4], sII[4];
    #pragma unroll
    for (int i = 0; i < 4; ++i) { sI[i] = z4; sp[i] = z4; sIp[i] = z4; sII[i] = z4; }

    int lo = h0 - r; if (lo < 0) lo = 0;
    int hi = h0 + r; if (hi > HD - 1) hi = HD - 1;
    for (int j = lo; j <= hi; ++j) {
        const float4* Ir = Ib + (size_t)j * ROW4;
        const float4* Pr = Pb + (size_t)j * ROW4;
        #pragma unroll
        for (int i = 0; i < 4; ++i) {
            float4 a = Ir[i], c = Pr[i];
            sI[i] = f4add(sI[i], a);
            sp[i] = f4add(sp[i], c);
            sIp[i].x += a.x * c.x; sIp[i].y += a.y * c.y;
            sIp[i].z += a.z * c.z; sIp[i].w += a.w * c.w;
            sII[i].x += a.x * a.x; sII[i].y += a.y * a.y;
            sII[i].z += a.z * a.z; sII[i].w += a.w * a.w;
        }
    }

    for (int h = h0; h < h0 + BH; ++h) {
        int hl = h - r; if (hl < 0) hl = 0;
        int hh = h + r; if (hh > HD - 1) hh = HD - 1;
        const float cntH = (float)(hh - hl + 1);

        // pass 1: sums of I and p
        scan2(Pfx, wtot, sI, sp, t, lane, wv);
        float4 S0[4], S1[4];
        #pragma unroll
        for (int i = 0; i < 4; ++i) {
            int wp = 4 * t + i;
            int wl = wp - r; if (wl < 0) wl = 0;
            int wh2 = wp + r; if (wh2 > WD - 1) wh2 = WD - 1;
            S0[i] = f4sub(Pfx[0][wh2 + 1], Pfx[0][wl]);
            S1[i] = f4sub(Pfx[1][wh2 + 1], Pfx[1][wl]);
        }
        __syncthreads();
        // pass 2: sums of Ip and II
        scan2(Pfx, wtot, sIp, sII, t, lane, wv);

        // prefetch slide rows (overlap with math below; drained at row-end sync)
        int ja = h + 1 + r, js = h - r;
        float wa  = (ja <= HD - 1) ? 1.f : 0.f;
        float wsb = (js >= 0) ? 1.f : 0.f;
        int jac = (ja <= HD - 1) ? ja : HD - 1;
        int jsc = (js >= 0) ? js : 0;
        const float4* Iar = Ib + (size_t)jac * ROW4;
        const float4* Par = Pb + (size_t)jac * ROW4;
        const float4* Isr = Ib + (size_t)jsc * ROW4;
        const float4* Psr = Pb + (size_t)jsc * ROW4;
        float4 a1[4], c1[4], a2[4], c2[4];
        #pragma unroll
        for (int i = 0; i < 4; ++i) { a1[i] = Iar[i]; c1[i] = Par[i]; a2[i] = Isr[i]; c2[i] = Psr[i]; }

        H4* Ar = Ao + (size_t)h * ROW4;
        H4* Br = Bo + (size_t)h * ROW4;
        #pragma unroll
        for (int i = 0; i < 4; ++i) {
            int wp = 4 * t + i;
            int wl = wp - r; if (wl < 0) wl = 0;
            int wh2 = wp + r; if (wh2 > WD - 1) wh2 = WD - 1;
            float invN = 1.f / ((float)(wh2 - wl + 1) * cntH);
            float4 mI  = f4s(S0[i], invN);
            float4 mp  = f4s(S1[i], invN);
            float4 mIp = f4s(f4sub(Pfx[0][wh2 + 1], Pfx[0][wl]), invN);
            float4 mII = f4s(f4sub(Pfx[1][wh2 + 1], Pfx[1][wl]), invN);
            float4 cov = f4sub(mIp, f4mul(mI, mp));
            float4 var = f4sub(mII, f4mul(mI, mI));
            float4 Av = make_float4(cov.x / (var.x + EPS), cov.y / (var.y + EPS),
                                    cov.z / (var.z + EPS), cov.w / (var.w + EPS));
            float4 Bv = f4sub(mp, f4mul(Av, mI));
            Ar[wp] = pack4(Av);
            Br[wp] = pack4(Bv);
        }
        __syncthreads();

        // slide window h -> h+1
        #pragma unroll
        for (int i = 0; i < 4; ++i) {
            float4 A1 = f4s(a1[i], wa),  C1 = f4s(c1[i], wa);
            float4 A2 = f4s(a2[i], wsb), C2 = f4s(c2[i], wsb);
            sI[i] = f4add(f4sub(sI[i], A2), A1);
            sp[i] = f4add(f4sub(sp[i], C2), C1);
            sIp[i].x += A1.x * C1.x - A2.x * C2.x; sIp[i].y += A1.y * C1.y - A2.y * C2.y;
            sIp[i].z += A1.z * C1.z - A2.z * C2.z; sIp[i].w += A1.w * C1.w - A2.w * C2.w;
            sII[i].x += A1.x * A1.x - A2.x * A2.x; sII[i].y += A1.y * A1.y - A2.y * A2.y;
            sII[i].z += A1.z * A1.z - A2.z * A2.z; sII[i].w += A1.w * A1.w - A2.w * A2.w;
        }
    }
}

// ---------------- KB: A,b -> q = meanA*I + meanb ----------------
__global__ __launch_bounds__(256, 1) void kfusedQ(
    const H4* __restrict__ Ain, const H4* __restrict__ Bin,
    const float4* __restrict__ I4, float4* __restrict__ Qout,
    const int* __restrict__ rptr)
{
    __shared__ float4 Pfx[2][ROW4 + 1];
    __shared__ float4 wtot[8];
    const int r = *rptr;
    const int t = threadIdx.x, lane = t & 63, wv = t >> 6;
    const int h0 = blockIdx.x * BH;
    const size_t imgb = (size_t)blockIdx.y * IMG4;
    const H4* Abp = Ain + imgb + 4 * t;
    const H4* Bbp = Bin + imgb + 4 * t;
    const float4* Ib = I4 + imgb + 4 * t;
    float4* Qo = Qout + imgb;
    const float4 z4 = make_float4(0.f, 0.f, 0.f, 0.f);

    float4 sA[4], sB[4];
    #pragma unroll
    for (int i = 0; i < 4; ++i) { sA[i] = z4; sB[i] = z4; }

    int lo = h0 - r; if (lo < 0) lo = 0;
    int hi = h0 + r; if (hi > HD - 1) hi = HD - 1;
    for (int j = lo; j <= hi; ++j) {
        const H4* Ar = Abp + (size_t)j * ROW4;
        const H4* Br = Bbp + (size_t)j * ROW4;
        #pragma unroll
        for (int i = 0; i < 4; ++i) {
            sA[i] = f4add(sA[i], unpack4(Ar[i]));
            sB[i] = f4add(sB[i], unpack4(Br[i]));
        }
    }

    for (int h = h0; h < h0 + BH; ++h) {
        int hl = h - r; if (hl < 0) hl = 0;
        int hh = h + r; if (hh > HD - 1) hh = HD - 1;
        const float cntH = (float)(hh - hl + 1);

        scan2(Pfx, wtot, sA, sB, t, lane, wv);

        // prefetch slide rows + I row
        int ja = h + 1 + r, js = h - r;
        float wa  = (ja <= HD - 1) ? 1.f : 0.f;
        float wsb = (js >= 0) ? 1.f : 0.f;
        int jac = (ja <= HD - 1) ? ja : HD - 1;
        int jsc = (js >= 0) ? js : 0;
        const H4* Aar = Abp + (size_t)jac * ROW4;
        const H4* Bar = Bbp + (size_t)jac * ROW4;
        const H4* Asr = Abp + (size_t)jsc * ROW4;
        const H4* Bsr = Bbp + (size_t)jsc * ROW4;
        const float4* Irow = Ib + (size_t)h * ROW4;
        H4 a1[4], b1[4], a2[4], b2[4];
        float4 iv[4];
        #pragma unroll
        for (int i = 0; i < 4; ++i) {
            a1[i] = Aar[i]; b1[i] = Bar[i];
            a2[i] = Asr[i]; b2[i] = Bsr[i];
            iv[i] = Irow[i];
        }

        float4* Qrow = Qo + (size_t)h * ROW4;
        #pragma unroll
        for (int i = 0; i < 4; ++i) {
            int wp = 4 * t + i;
            int wl = wp - r; if (wl < 0) wl = 0;
            int wh2 = wp + r; if (wh2 > WD - 1) wh2 = WD - 1;
            float invN = 1.f / ((float)(wh2 - wl + 1) * cntH);
            float4 mA = f4s(f4sub(Pfx[0][wh2 + 1], Pfx[0][wl]), invN);
            float4 mB = f4s(f4sub(Pfx[1][wh2 + 1], Pfx[1][wl]), invN);
            float4 q = make_float4(mA.x * iv[i].x + mB.x, mA.y * iv[i].y + mB.y,
                                   mA.z * iv[i].z + mB.z, mA.w * iv[i].w + mB.w);
            Qrow[wp] = q;
        }
        __syncthreads();

        // slide
        #pragma unroll
        for (int i = 0; i < 4; ++i) {
            float4 A1 = f4s(unpack4(a1[i]), wa),  B1 = f4s(unpack4(b1[i]), wa);
            float4 A2 = f4s(unpack4(a2[i]), wsb), B2 = f4s(unpack4(b2[i]), wsb);
            sA[i] = f4add(f4sub(sA[i], A2), A1);
            sB[i] = f4add(f4sub(sB[i], B2), B1);
        }
    }
}

extern "C" void kernel_launch(void* const* d_in, const int* in_sizes, int n_in,
                              void* d_out, int out_size, void* d_ws, size_t ws_size,
                              hipStream_t stream)
{
    const float* I = (const float*)d_in[0];
    const float* P = (const float*)d_in[1];
    const int* rptr = (const int*)d_in[2];
    float* out = (float*)d_out;

    const int Bn = (int)(in_sizes[0] / IMGF);              // 4
    const size_t perBatch = 2 * IMG4 * sizeof(H4);         // A,b fp16 = 16 MiB

    int nbChunk = (int)(ws_size / perBatch);
    if (nbChunk < 1) nbChunk = 1;
    if (nbChunk > Bn) nbChunk = Bn;

    for (int b0 = 0; b0 < Bn; b0 += nbChunk) {
        const int nb = (b0 + nbChunk <= Bn) ? nbChunk : (Bn - b0);
        H4* Ah = (H4*)d_ws;
        H4* Bh = Ah + (size_t)nb * IMG4;
        const float4* Ib = (const float4*)(I + (size_t)b0 * IMGF);
        const float4* Pb = (const float4*)(P + (size_t)b0 * IMGF);
        float4* ob = (float4*)(out + (size_t)b0 * IMGF);

        kfusedAB<<<dim3(NB, nb), 256, 0, stream>>>(Ib, Pb, Ah, Bh, rptr);
        kfusedQ<<<dim3(NB, nb), 256, 0, stream>>>(Ah, Bh, Ib, ob, rptr);
    }
}

// Round 5
// 253.229 us; speedup vs baseline: 1.9703x; 1.0520x over previous
//
#include <hip/hip_runtime.h>
#include <hip/hip_fp16.h>

// Guided filter, B=4 H=1024 W=1024 C=4 f32 NHWC, r from d_in[2] (expected 40).
// Fused per box-pass (R4 structure), R4->R5 changes:
//  - LDS prefix arrays are per-field float4 planes with pad-swizzle
//    idx4(p)=p+(p>>3): lane-stride-4 scan reads/writes now spread over all
//    32 banks (R4 blocked layout was ~16-way conflicted, 1.2e7 conflicts).
//  - scan4: all 4 fields in one block-scan -> 3 syncthreads/row (was 5).
//  - warm-up loads batched (2-4 rows in flight) to break the 81-row
//    latency-serialized chain; slide loads issued before the scan.
// kfusedAB: I,p -> vertical sliding sums {I,p,Ip,II} in registers; per row
//           block-wide prefix scan -> horizontal box; A,b out (fp16).
// kfusedQ : same over {A,b}; q = meanA*I + meanb -> d_out (f32).
// N = cntH(h)*cntW(w) analytic.

#define HD 1024
#define WD 1024
#define ROW4 WD                      // float4 pixels per row
#define IMG4 ((size_t)HD * ROW4)     // pixels per image
#define IMGF (IMG4 * 4)              // floats per image
#define BH 16                        // output rows per block
#define NB (HD / BH)                 // 64 bands
#define EPS 1e-8f
#define PFXN 1153                    // idx4(1024) = 1152, +1

__device__ __forceinline__ int idx4(int p) { return p + (p >> 3); }

struct H4 { __half2 lo, hi; };       // one fp16 pixel (4 channels)

__device__ __forceinline__ H4 pack4(float4 v) {
    H4 h; h.lo = __floats2half2_rn(v.x, v.y); h.hi = __floats2half2_rn(v.z, v.w);
    return h;
}
__device__ __forceinline__ float4 unpack4(H4 h) {
    float2 l = __half22float2(h.lo), u = __half22float2(h.hi);
    return make_float4(l.x, l.y, u.x, u.y);
}
__device__ __forceinline__ float4 f4add(float4 a, float4 b) {
    return make_float4(a.x + b.x, a.y + b.y, a.z + b.z, a.w + b.w);
}
__device__ __forceinline__ float4 f4sub(float4 a, float4 b) {
    return make_float4(a.x - b.x, a.y - b.y, a.z - b.z, a.w - b.w);
}
__device__ __forceinline__ float4 f4s(float4 a, float s) {
    return make_float4(a.x * s, a.y * s, a.z * s, a.w * s);
}
__device__ __forceinline__ float4 f4mul(float4 a, float4 b) {
    return make_float4(a.x * b.x, a.y * b.y, a.z * b.z, a.w * b.w);
}
__device__ __forceinline__ float4 shup4(float4 v, int d) {
    return make_float4(__shfl_up(v.x, d), __shfl_up(v.y, d), __shfl_up(v.z, d), __shfl_up(v.w, d));
}

// Block-wide inclusive prefix of 4 fields into swizzled planes pl[f][idx4(p)],
// pl[f][idx4(0)] = 0, pl[f][idx4(p)] = sum of first p pixels. 2 internal syncs.
__device__ __forceinline__ void scan4(
    float4 (*pl)[PFXN], float4 (*wtot)[4],
    const float4* s0, const float4* s1, const float4* s2, const float4* s3,
    int t, int lane, int wv)
{
    const float4 z4 = make_float4(0.f, 0.f, 0.f, 0.f);
    float4 p0[4], p1[4], p2[4], p3[4];
    p0[0] = s0[0]; p1[0] = s1[0]; p2[0] = s2[0]; p3[0] = s3[0];
    #pragma unroll
    for (int i = 1; i < 4; ++i) {
        p0[i] = f4add(p0[i-1], s0[i]); p1[i] = f4add(p1[i-1], s1[i]);
        p2[i] = f4add(p2[i-1], s2[i]); p3[i] = f4add(p3[i-1], s3[i]);
    }
    float4 i0 = p0[3], i1 = p1[3], i2 = p2[3], i3 = p3[3];
    #pragma unroll
    for (int d = 1; d < 64; d <<= 1) {
        float4 t0 = shup4(i0, d), t1 = shup4(i1, d), t2 = shup4(i2, d), t3 = shup4(i3, d);
        if (lane >= d) {
            i0 = f4add(i0, t0); i1 = f4add(i1, t1);
            i2 = f4add(i2, t2); i3 = f4add(i3, t3);
        }
    }
    float4 e0 = shup4(i0, 1), e1 = shup4(i1, 1), e2 = shup4(i2, 1), e3 = shup4(i3, 1);
    if (lane == 0) { e0 = z4; e1 = z4; e2 = z4; e3 = z4; }
    if (lane == 63) { wtot[wv][0] = i0; wtot[wv][1] = i1; wtot[wv][2] = i2; wtot[wv][3] = i3; }
    __syncthreads();
    for (int wq = 0; wq < wv; ++wq) {
        e0 = f4add(e0, wtot[wq][0]); e1 = f4add(e1, wtot[wq][1]);
        e2 = f4add(e2, wtot[wq][2]); e3 = f4add(e3, wtot[wq][3]);
    }
    if (t == 0) {
        pl[0][idx4(0)] = z4; pl[1][idx4(0)] = z4;
        pl[2][idx4(0)] = z4; pl[3][idx4(0)] = z4;
    }
    #pragma unroll
    for (int i = 0; i < 4; ++i) {
        int p = 4 * t + 1 + i;
        pl[0][idx4(p)] = f4add(e0, p0[i]);
        pl[1][idx4(p)] = f4add(e1, p1[i]);
        pl[2][idx4(p)] = f4add(e2, p2[i]);
        pl[3][idx4(p)] = f4add(e3, p3[i]);
    }
    __syncthreads();
}

// Same for 2 fields.
__device__ __forceinline__ void scan2s(
    float4 (*pl)[PFXN], float4 (*wtot)[2],
    const float4* s0, const float4* s1, int t, int lane, int wv)
{
    const float4 z4 = make_float4(0.f, 0.f, 0.f, 0.f);
    float4 p0[4], p1[4];
    p0[0] = s0[0]; p1[0] = s1[0];
    #pragma unroll
    for (int i = 1; i < 4; ++i) {
        p0[i] = f4add(p0[i-1], s0[i]); p1[i] = f4add(p1[i-1], s1[i]);
    }
    float4 i0 = p0[3], i1 = p1[3];
    #pragma unroll
    for (int d = 1; d < 64; d <<= 1) {
        float4 t0 = shup4(i0, d), t1 = shup4(i1, d);
        if (lane >= d) { i0 = f4add(i0, t0); i1 = f4add(i1, t1); }
    }
    float4 e0 = shup4(i0, 1), e1 = shup4(i1, 1);
    if (lane == 0) { e0 = z4; e1 = z4; }
    if (lane == 63) { wtot[wv][0] = i0; wtot[wv][1] = i1; }
    __syncthreads();
    for (int wq = 0; wq < wv; ++wq) {
        e0 = f4add(e0, wtot[wq][0]); e1 = f4add(e1, wtot[wq][1]);
    }
    if (t == 0) { pl[0][idx4(0)] = z4; pl[1][idx4(0)] = z4; }
    #pragma unroll
    for (int i = 0; i < 4; ++i) {
        int p = 4 * t + 1 + i;
        pl[0][idx4(p)] = f4add(e0, p0[i]);
        pl[1][idx4(p)] = f4add(e1, p1[i]);
    }
    __syncthreads();
}

// ---------------- KA: I,p -> A,b (fp16) ----------------
__global__ __launch_bounds__(256, 1) void kfusedAB(
    const float4* __restrict__ I4, const float4* __restrict__ P4,
    H4* __restrict__ Aout, H4* __restrict__ Bout,
    const int* __restrict__ rptr)
{
    __shared__ float4 Pfx[4][PFXN];       // 73.8 KB, swizzled planes
    __shared__ float4 wtot[4][4];
    const int r = *rptr;
    const int t = threadIdx.x, lane = t & 63, wv = t >> 6;
    const int h0 = blockIdx.x * BH;
    const size_t imgb = (size_t)blockIdx.y * IMG4;
    const float4* Ib = I4 + imgb + 4 * t;
    const float4* Pb = P4 + imgb + 4 * t;
    H4* Ao = Aout + imgb;
    H4* Bo = Bout + imgb;
    const float4 z4 = make_float4(0.f, 0.f, 0.f, 0.f);

    float4 sI[4], sp[4], sIp[4], sII[4];
    #pragma unroll
    for (int i = 0; i < 4; ++i) { sI[i] = z4; sp[i] = z4; sIp[i] = z4; sII[i] = z4; }

    int lo = h0 - r; if (lo < 0) lo = 0;
    int hi = h0 + r; if (hi > HD - 1) hi = HD - 1;
    // warm-up, 2 rows batched for MLP
    int j = lo;
    for (; j + 1 <= hi; j += 2) {
        const float4* Ir0 = Ib + (size_t)j * ROW4;
        const float4* Pr0 = Pb + (size_t)j * ROW4;
        const float4* Ir1 = Ib + (size_t)(j + 1) * ROW4;
        const float4* Pr1 = Pb + (size_t)(j + 1) * ROW4;
        float4 a0[4], c0[4], a1[4], c1[4];
        #pragma unroll
        for (int i = 0; i < 4; ++i) { a0[i] = Ir0[i]; c0[i] = Pr0[i]; a1[i] = Ir1[i]; c1[i] = Pr1[i]; }
        #pragma unroll
        for (int i = 0; i < 4; ++i) {
            sI[i] = f4add(sI[i], f4add(a0[i], a1[i]));
            sp[i] = f4add(sp[i], f4add(c0[i], c1[i]));
            sIp[i].x += a0[i].x*c0[i].x + a1[i].x*c1[i].x;
            sIp[i].y += a0[i].y*c0[i].y + a1[i].y*c1[i].y;
            sIp[i].z += a0[i].z*c0[i].z + a1[i].z*c1[i].z;
            sIp[i].w += a0[i].w*c0[i].w + a1[i].w*c1[i].w;
            sII[i].x += a0[i].x*a0[i].x + a1[i].x*a1[i].x;
            sII[i].y += a0[i].y*a0[i].y + a1[i].y*a1[i].y;
            sII[i].z += a0[i].z*a0[i].z + a1[i].z*a1[i].z;
            sII[i].w += a0[i].w*a0[i].w + a1[i].w*a1[i].w;
        }
    }
    if (j <= hi) {
        const float4* Ir0 = Ib + (size_t)j * ROW4;
        const float4* Pr0 = Pb + (size_t)j * ROW4;
        #pragma unroll
        for (int i = 0; i < 4; ++i) {
            float4 a = Ir0[i], c = Pr0[i];
            sI[i] = f4add(sI[i], a); sp[i] = f4add(sp[i], c);
            sIp[i].x += a.x*c.x; sIp[i].y += a.y*c.y; sIp[i].z += a.z*c.z; sIp[i].w += a.w*c.w;
            sII[i].x += a.x*a.x; sII[i].y += a.y*a.y; sII[i].z += a.z*a.z; sII[i].w += a.w*a.w;
        }
    }

    for (int h = h0; h < h0 + BH; ++h) {
        int hl = h - r; if (hl < 0) hl = 0;
        int hh = h + r; if (hh > HD - 1) hh = HD - 1;
        const float cntH = (float)(hh - hl + 1);

        // early-issue slide rows (consumed at end of iteration)
        int ja = h + 1 + r, js = h - r;
        float wa  = (ja <= HD - 1) ? 1.f : 0.f;
        float wsb = (js >= 0) ? 1.f : 0.f;
        int jac = (ja <= HD - 1) ? ja : HD - 1;
        int jsc = (js >= 0) ? js : 0;
        const float4* Iar = Ib + (size_t)jac * ROW4;
        const float4* Par = Pb + (size_t)jac * ROW4;
        const float4* Isr = Ib + (size_t)jsc * ROW4;
        const float4* Psr = Pb + (size_t)jsc * ROW4;
        float4 a1[4], c1[4], a2[4], c2[4];
        #pragma unroll
        for (int i = 0; i < 4; ++i) { a1[i] = Iar[i]; c1[i] = Par[i]; a2[i] = Isr[i]; c2[i] = Psr[i]; }

        scan4(Pfx, wtot, sI, sp, sIp, sII, t, lane, wv);

        H4* Ar = Ao + (size_t)h * ROW4;
        H4* Br = Bo + (size_t)h * ROW4;
        #pragma unroll
        for (int i = 0; i < 4; ++i) {
            int wp = 4 * t + i;
            int wl = wp - r; if (wl < 0) wl = 0;
            int wh2 = wp + r; if (wh2 > WD - 1) wh2 = WD - 1;
            float invN = 1.f / ((float)(wh2 - wl + 1) * cntH);
            int iA = idx4(wh2 + 1), iB = idx4(wl);
            float4 mI  = f4s(f4sub(Pfx[0][iA], Pfx[0][iB]), invN);
            float4 mp  = f4s(f4sub(Pfx[1][iA], Pfx[1][iB]), invN);
            float4 mIp = f4s(f4sub(Pfx[2][iA], Pfx[2][iB]), invN);
            float4 mII = f4s(f4sub(Pfx[3][iA], Pfx[3][iB]), invN);
            float4 cov = f4sub(mIp, f4mul(mI, mp));
            float4 var = f4sub(mII, f4mul(mI, mI));
            float4 Av = make_float4(cov.x / (var.x + EPS), cov.y / (var.y + EPS),
                                    cov.z / (var.z + EPS), cov.w / (var.w + EPS));
            float4 Bv = f4sub(mp, f4mul(Av, mI));
            Ar[wp] = pack4(Av);
            Br[wp] = pack4(Bv);
        }
        __syncthreads();

        // slide window h -> h+1
        #pragma unroll
        for (int i = 0; i < 4; ++i) {
            float4 A1 = f4s(a1[i], wa),  C1 = f4s(c1[i], wa);
            float4 A2 = f4s(a2[i], wsb), C2 = f4s(c2[i], wsb);
            sI[i] = f4add(f4sub(sI[i], A2), A1);
            sp[i] = f4add(f4sub(sp[i], C2), C1);
            sIp[i].x += A1.x*C1.x - A2.x*C2.x; sIp[i].y += A1.y*C1.y - A2.y*C2.y;
            sIp[i].z += A1.z*C1.z - A2.z*C2.z; sIp[i].w += A1.w*C1.w - A2.w*C2.w;
            sII[i].x += A1.x*A1.x - A2.x*A2.x; sII[i].y += A1.y*A1.y - A2.y*A2.y;
            sII[i].z += A1.z*A1.z - A2.z*A2.z; sII[i].w += A1.w*A1.w - A2.w*A2.w;
        }
    }
}

// ---------------- KB: A,b -> q = meanA*I + meanb ----------------
__global__ __launch_bounds__(256, 1) void kfusedQ(
    const H4* __restrict__ Ain, const H4* __restrict__ Bin,
    const float4* __restrict__ I4, float4* __restrict__ Qout,
    const int* __restrict__ rptr)
{
    __shared__ float4 Pfx[2][PFXN];       // 36.9 KB
    __shared__ float4 wtot[4][2];
    const int r = *rptr;
    const int t = threadIdx.x, lane = t & 63, wv = t >> 6;
    const int h0 = blockIdx.x * BH;
    const size_t imgb = (size_t)blockIdx.y * IMG4;
    const H4* Abp = Ain + imgb + 4 * t;
    const H4* Bbp = Bin + imgb + 4 * t;
    const float4* Ib = I4 + imgb + 4 * t;
    float4* Qo = Qout + imgb;
    const float4 z4 = make_float4(0.f, 0.f, 0.f, 0.f);

    float4 sA[4], sB[4];
    #pragma unroll
    for (int i = 0; i < 4; ++i) { sA[i] = z4; sB[i] = z4; }

    int lo = h0 - r; if (lo < 0) lo = 0;
    int hi = h0 + r; if (hi > HD - 1) hi = HD - 1;
    // warm-up, 4 rows batched
    int j = lo;
    for (; j + 3 <= hi; j += 4) {
        H4 a[4][4], b[4][4];
        #pragma unroll
        for (int k = 0; k < 4; ++k) {
            const H4* Ar = Abp + (size_t)(j + k) * ROW4;
            const H4* Br = Bbp + (size_t)(j + k) * ROW4;
            #pragma unroll
            for (int i = 0; i < 4; ++i) { a[k][i] = Ar[i]; b[k][i] = Br[i]; }
        }
        #pragma unroll
        for (int k = 0; k < 4; ++k)
            #pragma unroll
            for (int i = 0; i < 4; ++i) {
                sA[i] = f4add(sA[i], unpack4(a[k][i]));
                sB[i] = f4add(sB[i], unpack4(b[k][i]));
            }
    }
    for (; j <= hi; ++j) {
        const H4* Ar = Abp + (size_t)j * ROW4;
        const H4* Br = Bbp + (size_t)j * ROW4;
        #pragma unroll
        for (int i = 0; i < 4; ++i) {
            sA[i] = f4add(sA[i], unpack4(Ar[i]));
            sB[i] = f4add(sB[i], unpack4(Br[i]));
        }
    }

    for (int h = h0; h < h0 + BH; ++h) {
        int hl = h - r; if (hl < 0) hl = 0;
        int hh = h + r; if (hh > HD - 1) hh = HD - 1;
        const float cntH = (float)(hh - hl + 1);

        // early-issue slide rows + I row
        int ja = h + 1 + r, js = h - r;
        float wa  = (ja <= HD - 1) ? 1.f : 0.f;
        float wsb = (js >= 0) ? 1.f : 0.f;
        int jac = (ja <= HD - 1) ? ja : HD - 1;
        int jsc = (js >= 0) ? js : 0;
        const H4* Aar = Abp + (size_t)jac * ROW4;
        const H4* Bar = Bbp + (size_t)jac * ROW4;
        const H4* Asr = Abp + (size_t)jsc * ROW4;
        const H4* Bsr = Bbp + (size_t)jsc * ROW4;
        const float4* Irow = Ib + (size_t)h * ROW4;
        H4 a1[4], b1[4], a2[4], b2[4];
        float4 iv[4];
        #pragma unroll
        for (int i = 0; i < 4; ++i) {
            a1[i] = Aar[i]; b1[i] = Bar[i];
            a2[i] = Asr[i]; b2[i] = Bsr[i];
            iv[i] = Irow[i];
        }

        scan2s(Pfx, wtot, sA, sB, t, lane, wv);

        float4* Qrow = Qo + (size_t)h * ROW4;
        #pragma unroll
        for (int i = 0; i < 4; ++i) {
            int wp = 4 * t + i;
            int wl = wp - r; if (wl < 0) wl = 0;
            int wh2 = wp + r; if (wh2 > WD - 1) wh2 = WD - 1;
            float invN = 1.f / ((float)(wh2 - wl + 1) * cntH);
            int iA = idx4(wh2 + 1), iB = idx4(wl);
            float4 mA = f4s(f4sub(Pfx[0][iA], Pfx[0][iB]), invN);
            float4 mB = f4s(f4sub(Pfx[1][iA], Pfx[1][iB]), invN);
            Qrow[wp] = make_float4(mA.x * iv[i].x + mB.x, mA.y * iv[i].y + mB.y,
                                   mA.z * iv[i].z + mB.z, mA.w * iv[i].w + mB.w);
        }
        __syncthreads();

        // slide
        #pragma unroll
        for (int i = 0; i < 4; ++i) {
            float4 A1 = f4s(unpack4(a1[i]), wa),  B1 = f4s(unpack4(b1[i]), wa);
            float4 A2 = f4s(unpack4(a2[i]), wsb), B2 = f4s(unpack4(b2[i]), wsb);
            sA[i] = f4add(f4sub(sA[i], A2), A1);
            sB[i] = f4add(f4sub(sB[i], B2), B1);
        }
    }
}

extern "C" void kernel_launch(void* const* d_in, const int* in_sizes, int n_in,
                              void* d_out, int out_size, void* d_ws, size_t ws_size,
                              hipStream_t stream)
{
    const float* I = (const float*)d_in[0];
    const float* P = (const float*)d_in[1];
    const int* rptr = (const int*)d_in[2];
    float* out = (float*)d_out;

    const int Bn = (int)(in_sizes[0] / IMGF);              // 4
    const size_t perBatch = 2 * IMG4 * sizeof(H4);         // A,b fp16 = 16 MiB

    int nbChunk = (int)(ws_size / perBatch);
    if (nbChunk < 1) nbChunk = 1;
    if (nbChunk > Bn) nbChunk = Bn;

    for (int b0 = 0; b0 < Bn; b0 += nbChunk) {
        const int nb = (b0 + nbChunk <= Bn) ? nbChunk : (Bn - b0);
        H4* Ah = (H4*)d_ws;
        H4* Bh = Ah + (size_t)nb * IMG4;
        const float4* Ib = (const float4*)(I + (size_t)b0 * IMGF);
        const float4* Pb = (const float4*)(P + (size_t)b0 * IMGF);
        float4* ob = (float4*)(out + (size_t)b0 * IMGF);

        kfusedAB<<<dim3(NB, nb), 256, 0, stream>>>(Ib, Pb, Ah, Bh, rptr);
        kfusedQ<<<dim3(NB, nb), 256, 0, stream>>>(Ah, Bh, Ib, ob, rptr);
    }
}